// Round 4
// baseline (259.635 us; speedup 1.0000x reference)
//
#include <hip/hip_runtime.h>
#include <hip/hip_bf16.h>

#define N_ 2048
#define D_ 128
#define B_ 8
#define BM 64
#define BK 64
#define JSPLIT 8
#define JCHUNK (N_ / JSPLIT)               // 256
#define NSTEPS (JCHUNK / BK)               // 4
#define NBLOCKS (B_ * (N_ / BM) * JSPLIT)  // 2048

typedef __attribute__((ext_vector_type(8))) short short8;
typedef __attribute__((ext_vector_type(4))) float f32x4;

__device__ __forceinline__ unsigned short f2bf(float x) {
  unsigned int u = __builtin_bit_cast(unsigned int, x);
  u += 0x7fffu + ((u >> 16) & 1u);   // RNE; finite inputs
  return (unsigned short)(u >> 16);
}

__device__ __forceinline__ short8 pack8(float4 a, float4 b) {
  short8 o;
  o[0] = (short)f2bf(a.x); o[1] = (short)f2bf(a.y);
  o[2] = (short)f2bf(a.z); o[3] = (short)f2bf(a.w);
  o[4] = (short)f2bf(b.x); o[5] = (short)f2bf(b.y);
  o[6] = (short)f2bf(b.z); o[7] = (short)f2bf(b.w);
  return o;
}

// Build VT[b][128][2048] = bf16(emb^T), hsq[b][2048] fp32; zero the output.
__global__ __launch_bounds__(256) void prep_kernel(
    const float* __restrict__ emb, unsigned short* __restrict__ vt,
    float* __restrict__ hsq, float* __restrict__ out) {
  __shared__ float semb[64 * 132];
  __shared__ float shsq[64];
  const int t = threadIdx.x;
  if (blockIdx.x == 0 && t == 0) out[0] = 0.0f;
  const int bb = blockIdx.x >> 5;
  const int j0 = (blockIdx.x & 31) << 6;
  const float* ebase = emb + ((size_t)(bb * N_ + j0)) * D_;
#pragma unroll
  for (int it = 0; it < 8; ++it) {
    int fidx = it * 1024 + t * 4;
    int j = fidx >> 7, d = fidx & 127;
    const float4 v = *(const float4*)(ebase + (size_t)j * D_ + d);
    *(float4*)&semb[j * 132 + d] = v;
  }
  __syncthreads();
  {
    int j = t >> 2, q = t & 3;
    const float* row = &semb[j * 132 + q * 32];
    float p = 0.f;
#pragma unroll
    for (int x = 0; x < 32; ++x) p += row[x] * row[x];
    p += __shfl_down(p, 2);
    p += __shfl_down(p, 1);
    if (q == 0) { shsq[j] = p; hsq[bb * N_ + j0 + j] = p; }
  }
  __syncthreads();
  unsigned short* vbase = vt + (size_t)bb * D_ * N_ + j0;
#pragma unroll
  for (int it = 0; it < 4; ++it) {
    int idx = it * 256 + t;
    int d = idx >> 3, jg = idx & 7;
    short8 o;
#pragma unroll
    for (int x = 0; x < 8; ++x)
      o[x] = (short)f2bf(semb[(jg * 8 + x) * 132 + d]);
    *(short8*)&vbase[(size_t)d * N_ + jg * 8] = o;
  }
}

// Barrier-free K-loop: A (adj) global->reg with end-of-body prefetch,
// B-fragments global->reg from L2-resident VT (16 B aligned contiguous).
// No LDS in the loop => no vmcnt(0) drains; waves self-overlap.
__global__ __launch_bounds__(256, 3) void gemm_kernel(
    const float* __restrict__ adj, const float* __restrict__ emb,
    const float* __restrict__ hsq, const unsigned short* __restrict__ vt,
    float* __restrict__ out) {
  __shared__ float red[4];
  const int t = threadIdx.x;
  const int lane = t & 63, wave = t >> 6;
  const int lhalf = lane & 15, quad = lane >> 4;
  const int bid = blockIdx.x;
  const int b = bid & 7;                     // XCD-affine batch
  const int rem = bid >> 3;
  const int i0 = (rem & 31) << 6;            // 32 i-tiles of 64
  const int j0 = (rem >> 5) * JCHUNK;        // 8 j-chunks of 256

  const unsigned short* vtb = vt + (size_t)b * D_ * N_;
  const float* embb = emb + (size_t)b * N_ * D_;
  const float* hsqb = hsq + b * N_;
  const int irow = i0 + wave * 16 + lhalf;   // A-operand m = lhalf
  const float* arow = adj + ((size_t)b << 22) + (size_t)irow * N_;
  const float hsqi = hsqb[irow];

  f32x4 acc[8] = {};
  float p1 = 0.f, p2 = 0.f;

  const float* ap = arow + j0 + quad * 8;    // k = quad*8 + x (+32 for ks=1)
  float4 a0 = *(const float4*)ap;
  float4 a1 = *(const float4*)(ap + 4);
  float4 a2 = *(const float4*)(ap + 32);
  float4 a3 = *(const float4*)(ap + 36);

#pragma unroll
  for (int ki = 0; ki < NSTEPS; ++ki) {
    const int jk = j0 + ki * BK;
    const float* hp = hsqb + jk + quad * 8;
    const float4 h0 = *(const float4*)hp;
    const float4 h1 = *(const float4*)(hp + 4);
    const float4 h2 = *(const float4*)(hp + 32);
    const float4 h3 = *(const float4*)(hp + 36);

    p1 += ((a0.x + a0.y + a0.z + a0.w) + (a1.x + a1.y + a1.z + a1.w)
         + (a2.x + a2.y + a2.z + a2.w) + (a3.x + a3.y + a3.z + a3.w)) * hsqi;
    p2 += a0.x*h0.x + a0.y*h0.y + a0.z*h0.z + a0.w*h0.w
        + a1.x*h1.x + a1.y*h1.y + a1.z*h1.z + a1.w*h1.w
        + a2.x*h2.x + a2.y*h2.y + a2.z*h2.z + a2.w*h2.w
        + a3.x*h3.x + a3.y*h3.y + a3.z*h3.z + a3.w*h3.w;

    short8 f0 = pack8(a0, a1);   // k = 0..7  (per quad block)
    short8 f1 = pack8(a2, a3);   // k = 32..39

    const unsigned short* vb = vtb + jk + quad * 8;
#pragma unroll
    for (int nt = 0; nt < 8; ++nt) {
      int r = nt * 16 + lhalf;               // n = d
      short8 b0 = *(const short8*)(vb + (size_t)r * N_);
      short8 b1 = *(const short8*)(vb + (size_t)r * N_ + 32);
      acc[nt] = __builtin_amdgcn_mfma_f32_16x16x32_bf16(f0, b0, acc[nt], 0, 0, 0);
      acc[nt] = __builtin_amdgcn_mfma_f32_16x16x32_bf16(f1, b1, acc[nt], 0, 0, 0);
    }
    if (ki + 1 < NSTEPS) {                   // prefetch next A AFTER B loads
      const float* apn = arow + jk + BK + quad * 8;
      a0 = *(const float4*)apn;
      a1 = *(const float4*)(apn + 4);
      a2 = *(const float4*)(apn + 32);
      a3 = *(const float4*)(apn + 36);
    }
  }

  // epilogue: C/D layout col(d)=lane&15, row(i)=quad*4+reg
  float pc = 0.f;
#pragma unroll
  for (int r = 0; r < 4; ++r) {
    int i = i0 + wave * 16 + quad * 4 + r;
    const float* erow = embb + (size_t)i * D_;
#pragma unroll
    for (int nt = 0; nt < 8; ++nt)
      pc += acc[nt][r] * erow[nt * 16 + lhalf];
  }
  float part = (p1 + p2 - 2.0f * pc) * (1.0f / ((float)B_ * (float)N_));
#pragma unroll
  for (int off = 32; off > 0; off >>= 1) part += __shfl_down(part, off);
  if (lane == 0) red[wave] = part;
  __syncthreads();
  if (t == 0) atomicAdd(out, red[0] + red[1] + red[2] + red[3]);
}

extern "C" void kernel_launch(void* const* d_in, const int* in_sizes, int n_in,
                              void* d_out, int out_size, void* d_ws, size_t ws_size,
                              hipStream_t stream) {
  const float* adj = (const float*)d_in[0];
  const float* emb = (const float*)d_in[1];
  float* hsq = (float*)d_ws;                                  // 64 KiB
  unsigned short* vt = (unsigned short*)((char*)d_ws + 65536); // 4 MiB

  prep_kernel<<<B_ * (N_ / 64), 256, 0, stream>>>(emb, vt, hsq, (float*)d_out);
  gemm_kernel<<<NBLOCKS, 256, 0, stream>>>(adj, emb, hsq, vt, (float*)d_out);
}

// Round 5
// 209.383 us; speedup vs baseline: 1.2400x; 1.2400x over previous
//
#include <hip/hip_runtime.h>
#include <hip/hip_bf16.h>

#define N_ 2048
#define D_ 128
#define B_ 8
#define BM 64
#define BKC 128                               // K-chunk (j extent) per block
#define NBLOCKS (B_ * (N_ / BM) * (N_ / BKC)) // 8*32*16 = 4096

typedef __attribute__((ext_vector_type(8))) short short8;
typedef __attribute__((ext_vector_type(4))) float f32x4;

__device__ __forceinline__ unsigned short f2bf(float x) {
  unsigned int u = __builtin_bit_cast(unsigned int, x);
  u += 0x7fffu + ((u >> 16) & 1u);   // RNE; finite inputs
  return (unsigned short)(u >> 16);
}

__device__ __forceinline__ void async_lds16(const void* g, void* l) {
  __builtin_amdgcn_global_load_lds(
      (const __attribute__((address_space(1))) void*)g,
      (__attribute__((address_space(3))) void*)l, 16, 0, 0);
}

__device__ __forceinline__ short8 pack8(float4 a, float4 b) {
  short8 o;
  o[0] = (short)f2bf(a.x); o[1] = (short)f2bf(a.y);
  o[2] = (short)f2bf(a.z); o[3] = (short)f2bf(a.w);
  o[4] = (short)f2bf(b.x); o[5] = (short)f2bf(b.y);
  o[6] = (short)f2bf(b.z); o[7] = (short)f2bf(b.w);
  return o;
}

// Build VT[b][128][2048] = bf16(emb^T), hsq[b][2048] fp32. Block = 64 nodes.
__global__ __launch_bounds__(256) void prep_kernel(
    const float* __restrict__ emb, unsigned short* __restrict__ vt,
    float* __restrict__ hsq) {
  __shared__ float semb[64 * 132];
  __shared__ float shsq[64];
  const int t = threadIdx.x;
  const int bb = blockIdx.x >> 5;
  const int j0 = (blockIdx.x & 31) << 6;
  const float* ebase = emb + ((size_t)(bb * N_ + j0)) * D_;
#pragma unroll
  for (int it = 0; it < 8; ++it) {
    int fidx = it * 1024 + t * 4;
    int j = fidx >> 7, d = fidx & 127;
    const float4 v = *(const float4*)(ebase + (size_t)j * D_ + d);
    *(float4*)&semb[j * 132 + d] = v;
  }
  __syncthreads();
  {
    int j = t >> 2, q = t & 3;
    const float* row = &semb[j * 132 + q * 32];
    float p = 0.f;
#pragma unroll
    for (int x = 0; x < 32; ++x) p += row[x] * row[x];
    p += __shfl_down(p, 2);
    p += __shfl_down(p, 1);
    if (q == 0) { shsq[j] = p; hsq[bb * N_ + j0 + j] = p; }
  }
  __syncthreads();
  unsigned short* vbase = vt + (size_t)bb * D_ * N_ + j0;
#pragma unroll
  for (int it = 0; it < 4; ++it) {
    int idx = it * 256 + t;
    int d = idx >> 3, jg = idx & 7;
    short8 o;
#pragma unroll
    for (int x = 0; x < 8; ++x)
      o[x] = (short)f2bf(semb[(jg * 8 + x) * 132 + d]);
    *(short8*)&vbase[(size_t)d * N_ + jg * 8] = o;
  }
}

// One staging phase per block: A global->reg (issued FIRST), V-tile 32 KB via
// global_load_lds (swizzled), ONE barrier where the wave has no work anyway,
// then a barrier-free LDS+MFMA phase. 4 blocks/CU provide the overlap.
__global__ __launch_bounds__(256, 4) void gemm_kernel(
    const float* __restrict__ adj, const float* __restrict__ emb,
    const float* __restrict__ hsq, const unsigned short* __restrict__ vt,
    float* __restrict__ partials) {
  __shared__ unsigned short lV[128 * BKC];   // [d][k], 16B units XOR-swizzled by d&15
  __shared__ float red[4];

  const int t = threadIdx.x;
  const int lane = t & 63, wave = t >> 6;
  const int lhalf = lane & 15, quad = lane >> 4;
  const int bid = blockIdx.x;
  const int b = bid & 7;                      // XCD-affine batch
  const int rem = bid >> 3;
  const int i0 = (rem & 31) << 6;             // 32 i-tiles of 64
  const int j0 = (rem >> 5) * BKC;            // 16 j-chunks of 128

  const unsigned short* vtb = vt + (size_t)b * D_ * N_;
  const float* embb = emb + (size_t)b * N_ * D_;
  const float* hsqb = hsq + b * N_;
  const int irow = i0 + wave * 16 + lhalf;    // A-operand m = lhalf
  const float* arow = adj + ((size_t)b << 22) + (size_t)irow * N_;
  const float hsqi = hsqb[irow];

  // --- issue A loads FIRST (vmcnt FIFO: A-wait won't force V drain)
  const float* ap = arow + j0 + quad * 8;     // k = s*32 + quad*8 + x
  float4 A[8];
#pragma unroll
  for (int s = 0; s < 4; ++s) {
    A[2 * s]     = *(const float4*)(ap + s * 32);
    A[2 * s + 1] = *(const float4*)(ap + s * 32 + 4);
  }
  // --- issue V staging: 128 rows x 256 B, swizzle in the global source addr
#pragma unroll
  for (int it = 0; it < 8; ++it) {
    int flat = it * 256 + t;
    int r = flat >> 4, u = flat & 15;
    async_lds16(vtb + (size_t)r * N_ + j0 + (u ^ (r & 15)) * 8,
                (char*)lV + (size_t)flat * 16);
  }
  // --- fp32 hsq terms + bf16 pack (waits only on A/h)
  float p1s = 0.f, p2 = 0.f;
  short8 f[4];
#pragma unroll
  for (int s = 0; s < 4; ++s) {
    const float4 h0 = *(const float4*)(hsqb + j0 + s * 32 + quad * 8);
    const float4 h1 = *(const float4*)(hsqb + j0 + s * 32 + quad * 8 + 4);
    const float4 a0 = A[2 * s], a1 = A[2 * s + 1];
    p1s += (a0.x + a0.y + a0.z + a0.w) + (a1.x + a1.y + a1.z + a1.w);
    p2  += a0.x * h0.x + a0.y * h0.y + a0.z * h0.z + a0.w * h0.w
         + a1.x * h1.x + a1.y * h1.y + a1.z * h1.z + a1.w * h1.w;
    f[s] = pack8(a0, a1);
  }
  __syncthreads();   // the ONLY barrier: drains V staging; wave is idle here anyway

  // --- pure LDS + MFMA phase (no barriers, fine lgkmcnt pipelining)
  f32x4 acc[8] = {};
#pragma unroll
  for (int s = 0; s < 4; ++s) {
#pragma unroll
    for (int nt = 0; nt < 8; ++nt) {
      int r = nt * 16 + lhalf;
      int u = (s * 4 + quad) ^ (r & 15);
      short8 bf = *(const short8*)((char*)lV + (size_t)(r * 16 + u) * 16);
      acc[nt] = __builtin_amdgcn_mfma_f32_16x16x32_bf16(f[s], bf, acc[nt], 0, 0, 0);
    }
  }

  // --- epilogue: C/D layout col(d)=lane&15, row(i)=quad*4+reg
  float pc = 0.f;
#pragma unroll
  for (int r = 0; r < 4; ++r) {
    int i = i0 + wave * 16 + quad * 4 + r;
    const float* erow = embb + (size_t)i * D_;
#pragma unroll
    for (int nt = 0; nt < 8; ++nt)
      pc += acc[nt][r] * erow[nt * 16 + lhalf];
  }
  float part = p1s * hsqi + p2 - 2.0f * pc;
#pragma unroll
  for (int off = 32; off > 0; off >>= 1) part += __shfl_down(part, off);
  if (lane == 0) red[wave] = part;
  __syncthreads();
  if (t == 0) partials[bid] = red[0] + red[1] + red[2] + red[3];
}

__global__ void finish_kernel(const float* __restrict__ partials,
                              float* __restrict__ out) {
  __shared__ double sred[4];
  const int t = threadIdx.x;
  double s = 0.0;
#pragma unroll
  for (int it = 0; it < NBLOCKS / 256; ++it)
    s += (double)partials[it * 256 + t];
#pragma unroll
  for (int off = 32; off > 0; off >>= 1) s += __shfl_down(s, off);
  if ((t & 63) == 0) sred[t >> 6] = s;
  __syncthreads();
  if (t == 0)
    out[0] = (float)((sred[0] + sred[1] + sred[2] + sred[3]) /
                     (double)((size_t)B_ * N_));
}

extern "C" void kernel_launch(void* const* d_in, const int* in_sizes, int n_in,
                              void* d_out, int out_size, void* d_ws, size_t ws_size,
                              hipStream_t stream) {
  const float* adj = (const float*)d_in[0];
  const float* emb = (const float*)d_in[1];
  float* hsq = (float*)d_ws;                                   // 64 KiB
  unsigned short* vt = (unsigned short*)((char*)d_ws + 65536); // 4 MiB
  float* partials = (float*)((char*)d_ws + 65536 + (size_t)B_ * D_ * N_ * 2);

  prep_kernel<<<B_ * (N_ / 64), 256, 0, stream>>>(emb, vt, hsq);
  gemm_kernel<<<NBLOCKS, 256, 0, stream>>>(adj, emb, hsq, vt, partials);
  finish_kernel<<<1, 256, 0, stream>>>(partials, (float*)d_out);
}